// Round 6
// baseline (697.585 us; speedup 1.0000x reference)
//
#include <hip/hip_runtime.h>
#include <hip/hip_fp16.h>

#define D4 512        // 2048 floats = 512 float4 per row (f32 rows)
#define T4 256        // 2048 halves = 256 float4 per row (fp16 rows)
#define K_EDGES 16    // sorted edges per wave-chunk
#define BAND_LO (-1.0f)   // ~50 sigma of two-sided fp16 quantization error
#define BAND_HI (2.0f)

// ========== fused: zero sort counters + build plain fp16 mirrors ==========
// Mirrors are used for BOTH heads and tails (120 MB steady-state set).
// rel applied in-registers at head-run switches (f32 rel row is L1-hot).
__global__ __launch_bounds__(256) void cvt_zero(
    const float4* __restrict__ xd, const float4* __restrict__ xp,
    __half* __restrict__ drug16, __half* __restrict__ prot16,
    int nd4, int np4, int* __restrict__ zp, int zn)
{
    const int stride = gridDim.x * blockDim.x;
    int i = blockIdx.x * blockDim.x + threadIdx.x;
    for (int k = i; k < zn; k += stride) zp[k] = 0;   // cheap, overlaps cvt
    const int total = nd4 + np4;
    for (; i < total; i += stride) {
        float4 v; __half* o; int idx;
        if (i < nd4) { v = xd[i]; o = drug16; idx = i; }
        else         { v = xp[i - nd4]; o = prot16; idx = i - nd4; }
        __half2 h01 = __floats2half2_rn(v.x, v.y);
        __half2 h23 = __floats2half2_rn(v.z, v.w);
        uint2 pk = make_uint2(*(const unsigned*)&h01, *(const unsigned*)&h23);
        ((uint2*)o)[idx] = pk;            // 4 halves per source float4
    }
}

__global__ void zero_ints(int* __restrict__ p, int n) {   // mid-tier path only
    int i = blockIdx.x * blockDim.x + threadIdx.x;
    if (i < n) p[i] = 0;
}

// ================= counting sort by (rel, src) ============================
// buckets: [0,ndp) rel0 | [ndp,2ndp) rel1 | [2ndp,2ndp+npp) rel2
__global__ void hist3(const int* __restrict__ s0, const int* __restrict__ s1,
                      const int* __restrict__ s2, int E,
                      int* __restrict__ cnt, int ndp) {
    int i = blockIdx.x * blockDim.x + threadIdx.x;
    const int total = 3 * E;
    for (; i < total; i += gridDim.x * blockDim.x) {
        if (i < E)           atomicAdd(&cnt[s0[i]], 1);
        else if (i < 2 * E)  atomicAdd(&cnt[ndp + s1[i - E]], 1);
        else                 atomicAdd(&cnt[2 * ndp + s2[i - 2 * E]], 1);
    }
}

// bump-alloc contiguous region per bucket: wave shfl-scan + 1 atomic/wave.
__global__ void alloc3(const int* __restrict__ cnt, int* __restrict__ base,
                       int* __restrict__ cursors, int ndp, int CB) {
    int i = blockIdx.x * blockDim.x + threadIdx.x;
    if (i >= CB) return;                   // whole waves only (ndp/npp 64-aligned)
    const int lane = threadIdx.x & 63;
    const int g = (i < ndp) ? 0 : (i < 2 * ndp) ? 1 : 2;   // wave-uniform
    int c = cnt[i];
    int x = c;
#pragma unroll
    for (int d = 1; d < 64; d <<= 1) {
        int y = __shfl_up(x, d, 64);
        if (lane >= d) x += y;
    }
    int tot = __shfl(x, 63);
    int wb = 0;
    if (lane == 63) wb = atomicAdd(&cursors[g], tot);
    wb = __shfl(wb, 63);
    base[i] = wb + x - c;                  // exclusive offset within relation
}

__global__ void scatter3(const int* __restrict__ s0, const int* __restrict__ d0_,
                         const int* __restrict__ s1, const int* __restrict__ d1_,
                         const int* __restrict__ s2, const int* __restrict__ d2_,
                         int E, int* __restrict__ base, int ndp,
                         int* __restrict__ sorted, int* __restrict__ sd) {
    int i = blockIdx.x * blockDim.x + threadIdx.x;
    const int total = 3 * E;
    for (; i < total; i += gridDim.x * blockDim.x) {
        if (i < E) {
            int s = s0[i], d = d0_[i];
            int p = atomicAdd(&base[s], 1);
            sorted[p] = i; sd[p] = (s << 16) | d;
        } else if (i < 2 * E) {
            int k = i - E; int s = s1[k], d = d1_[k];
            int p = atomicAdd(&base[ndp + s], 1);
            sorted[E + p] = k; sd[E + p] = (s << 16) | d;
        } else {
            int k = i - 2 * E; int s = s2[k], d = d2_[k];
            int p = atomicAdd(&base[2 * ndp + s], 1);
            sorted[2 * E + p] = k; sd[2 * E + p] = (s << 16) | d;
        }
    }
}

// ============ fp16 scoring + INLINE f32 refine of borderline edges ========
// Head AND tail from fp16 mirrors. hr = fp16(head)*rel_f32 per src-run.
// Borderline edges (pre-clip score in the band) are recomputed exactly in
// f32 by the SAME wave immediately — overlapped with other waves' streams,
// no separate dispatch. All other edges saturate to 0/1 identically to ref.
// Dynamic chunk queue removes the 2.3-chunks/wave static-stride tail idle.
__global__ __launch_bounds__(256) void score16(
    const float4* __restrict__ drug16, const float4* __restrict__ prot16,
    const float4* __restrict__ xdrug, const float4* __restrict__ xprot,
    const float4* __restrict__ rddi,  const float4* __restrict__ rdpi,
    const int* __restrict__ sorted, const int* __restrict__ sd,
    int* __restrict__ queue, float* __restrict__ out, int E)
{
    const int lane = threadIdx.x & 63;
    const int wpb = blockDim.x >> 6;
    const int wid = blockIdx.x * wpb + (threadIdx.x >> 6);
    const int nw = gridDim.x * wpb;
    const int cpr = (E + K_EDGES - 1) / K_EDGES;
    const int total_chunks = 3 * cpr;

    int c = wid;
    while (c < total_chunks) {
        const int r = (c >= 2 * cpr) ? 2 : (c >= cpr) ? 1 : 0;
        const int ci = c - r * cpr;
        const int e_lo = ci * K_EDGES;
        const int n = min(K_EDGES, E - e_lo);

        const float4* xh   = (r < 2)  ? drug16 : prot16;  // head (fp16)
        const float4* xt   = (r == 0) ? drug16 : prot16;  // tail (fp16)
        const float4* xh32 = (r < 2)  ? xdrug  : xprot;   // exact sources
        const float4* xt32 = (r == 0) ? xdrug  : xprot;
        const float4* rel  = (r == 0) ? rddi   : rdpi;    // f32, L1-hot
        const int* sl  = sorted + (size_t)r * E + e_lo;
        const int* sdl = sd     + (size_t)r * E + e_lo;
        float* o = out + (size_t)r * E;

        int eL = 0, sdL = 0;               // chunk metadata in lanes, shfl out
        if (lane < n) { eL = sl[lane]; sdL = sdl[lane]; }

        float4 hr[8];
        int cur = -1;

        for (int i = 0; i < n; ++i) {
            const int sdi = __shfl(sdL, i);   // convergent: whole wave
            const int e   = __shfl(eL, i);    // convergent: whole wave
            const int s = sdi >> 16;
            const int d = sdi & 0xffff;
            if (s != cur) {                // wave-uniform branch
                cur = s;
                const float4* hp = xh + (size_t)s * T4;
#pragma unroll
                for (int g = 0; g < 4; ++g) {
                    float4 hv = hp[g * 64 + lane];
                    const __half2* h2 = (const __half2*)&hv;
                    float4 r0 = rel[2 * (g * 64 + lane)];
                    float4 r1 = rel[2 * (g * 64 + lane) + 1];
                    float2 f0 = __half22float2(h2[0]);
                    float2 f1 = __half22float2(h2[1]);
                    float2 f2 = __half22float2(h2[2]);
                    float2 f3 = __half22float2(h2[3]);
                    hr[2 * g].x     = f0.x * r0.x;
                    hr[2 * g].y     = f0.y * r0.y;
                    hr[2 * g].z     = f1.x * r0.z;
                    hr[2 * g].w     = f1.y * r0.w;
                    hr[2 * g + 1].x = f2.x * r1.x;
                    hr[2 * g + 1].y = f2.y * r1.y;
                    hr[2 * g + 1].z = f3.x * r1.z;
                    hr[2 * g + 1].w = f3.y * r1.w;
                }
            }
            const float4* tq = xt + (size_t)d * T4;
            float a0 = 0.f, a1 = 0.f, a2 = 0.f, a3 = 0.f;
#pragma unroll
            for (int g = 0; g < 4; ++g) {
                float4 tv = tq[g * 64 + lane];
                const __half2* t2 = (const __half2*)&tv;
                float2 f0 = __half22float2(t2[0]);
                float2 f1 = __half22float2(t2[1]);
                float2 f2 = __half22float2(t2[2]);
                float2 f3 = __half22float2(t2[3]);
                a0 = fmaf(hr[2 * g].x, f0.x, a0);
                a1 = fmaf(hr[2 * g].y, f0.y, a1);
                a2 = fmaf(hr[2 * g].z, f1.x, a2);
                a3 = fmaf(hr[2 * g].w, f1.y, a3);
                a0 = fmaf(hr[2 * g + 1].x, f2.x, a0);
                a1 = fmaf(hr[2 * g + 1].y, f2.y, a1);
                a2 = fmaf(hr[2 * g + 1].z, f3.x, a2);
                a3 = fmaf(hr[2 * g + 1].w, f3.y, a3);
            }
            float acc = (a0 + a1) + (a2 + a3);
#pragma unroll
            for (int off = 32; off; off >>= 1) acc += __shfl_down(acc, off, 64);
            const float accb = __shfl(acc, 0);     // broadcast final sum

            if (accb > BAND_LO && accb < BAND_HI) {
                // exact f32 recompute, wave-uniform (~2-3% of edges)
                const float4* hp32 = xh32 + (size_t)s * D4;
                const float4* tp32 = xt32 + (size_t)d * D4;
                float b0 = 0.f, b1 = 0.f, b2 = 0.f, b3 = 0.f;
#pragma unroll
                for (int j = 0; j < 8; ++j) {
                    const int idx = j * 64 + lane;
                    float4 h = hp32[idx], t = tp32[idx], rv = rel[idx];
                    b0 = fmaf(h.x * rv.x, t.x, b0);
                    b1 = fmaf(h.y * rv.y, t.y, b1);
                    b2 = fmaf(h.z * rv.z, t.z, b2);
                    b3 = fmaf(h.w * rv.w, t.w, b3);
                }
                float bcc = (b0 + b1) + (b2 + b3);
#pragma unroll
                for (int off = 32; off; off >>= 1) bcc += __shfl_down(bcc, off, 64);
                if (lane == 0) o[e] = fminf(fmaxf(bcc, 0.f), 1.f);
            } else if (lane == 0) {
                o[e] = fminf(fmaxf(accb, 0.f), 1.f);
            }
        }

        // dynamic work queue: even chunk distribution regardless of runtime
        int nc = 0;
        if (lane == 0) nc = atomicAdd(queue, 1);
        c = nw + __shfl(nc, 0);
    }
}

// ================= mid-tier: f32 sorted path ==============================
__global__ __launch_bounds__(256) void score_f32(
    const float4* __restrict__ xdrug, const float4* __restrict__ xprot,
    const float4* __restrict__ rddi,  const float4* __restrict__ rdpi,
    const int* __restrict__ sorted, const int* __restrict__ sd,
    float* __restrict__ out, int E)
{
    const int lane = threadIdx.x & 63;
    const int wpb = blockDim.x >> 6;
    const int wid = blockIdx.x * wpb + (threadIdx.x >> 6);
    const int nw = gridDim.x * wpb;
    const int cpr = (E + K_EDGES - 1) / K_EDGES;
    const int total_chunks = 3 * cpr;

    for (int c = wid; c < total_chunks; c += nw) {
        const int r = (c >= 2 * cpr) ? 2 : (c >= cpr) ? 1 : 0;
        const int ci = c - r * cpr;
        const int e_lo = ci * K_EDGES;
        const int n = min(K_EDGES, E - e_lo);

        const float4 *xs, *xd, *rel;
        if (r == 0)      { xs = xdrug; xd = xdrug; rel = rddi; }
        else if (r == 1) { xs = xdrug; xd = xprot; rel = rdpi; }
        else             { xs = xprot; xd = xprot; rel = rdpi; }
        const int* sl  = sorted + (size_t)r * E + e_lo;
        const int* sdl = sd     + (size_t)r * E + e_lo;
        float* o = out + (size_t)r * E;

        float4 hr[8];
        int cur = -1;
        for (int i = 0; i < n; ++i) {
            const int e = sl[i];
            const int sdi = sdl[i];
            const int s = sdi >> 16;
            if (s != cur) {
                cur = s;
                const float4* hp = xs + (size_t)s * D4;
#pragma unroll
                for (int j = 0; j < 8; ++j) {
                    float4 h = hp[j * 64 + lane], rv = rel[j * 64 + lane];
                    hr[j].x = h.x * rv.x; hr[j].y = h.y * rv.y;
                    hr[j].z = h.z * rv.z; hr[j].w = h.w * rv.w;
                }
            }
            const float4* tp = xd + (size_t)(sdi & 0xffff) * D4;
            float acc = 0.f;
#pragma unroll
            for (int j = 0; j < 8; ++j) {
                float4 t = tp[j * 64 + lane];
                acc = fmaf(hr[j].x, t.x, acc);
                acc = fmaf(hr[j].y, t.y, acc);
                acc = fmaf(hr[j].z, t.z, acc);
                acc = fmaf(hr[j].w, t.w, acc);
            }
#pragma unroll
            for (int off = 32; off; off >>= 1) acc += __shfl_down(acc, off, 64);
            if (lane == 0) o[e] = fminf(fmaxf(acc, 0.f), 1.f);
        }
    }
}

// ================= last-resort direct kernel ==============================
__global__ __launch_bounds__(256) void edge_score_all(
    const float4* __restrict__ xdrug, const float4* __restrict__ xprot,
    const float4* __restrict__ rddi,  const float4* __restrict__ rdpi,
    const int* __restrict__ ddi_src, const int* __restrict__ ddi_dst,
    const int* __restrict__ dpi_src, const int* __restrict__ dpi_dst,
    const int* __restrict__ ppi_src, const int* __restrict__ ppi_dst,
    float* __restrict__ out, int E)
{
    __shared__ float4 srel[2][D4];
    for (int i = threadIdx.x; i < D4; i += blockDim.x) {
        srel[0][i] = rddi[i];
        srel[1][i] = rdpi[i];
    }
    __syncthreads();
    const int lane = threadIdx.x & 63;
    const int wpb = blockDim.x >> 6;
    int wid = blockIdx.x * wpb + (threadIdx.x >> 6);
    const int nw = gridDim.x * wpb;
    const int total = 3 * E;
    for (int e = wid; e < total; e += nw) {
        const float4 *hp, *tp;
        int sel;
        if (e < E)          { hp = xdrug + (size_t)ddi_src[e] * D4; tp = xdrug + (size_t)ddi_dst[e] * D4; sel = 0; }
        else if (e < 2 * E) { int k = e - E;     hp = xdrug + (size_t)dpi_src[k] * D4; tp = xprot + (size_t)dpi_dst[k] * D4; sel = 1; }
        else                { int k = e - 2 * E; hp = xprot + (size_t)ppi_src[k] * D4; tp = xprot + (size_t)ppi_dst[k] * D4; sel = 1; }
        float acc = 0.f;
#pragma unroll
        for (int j = 0; j < 8; ++j) {
            const int idx = j * 64 + lane;
            float4 h = hp[idx], t = tp[idx], rr = srel[sel][idx];
            acc = fmaf(h.x * rr.x, t.x, acc);
            acc = fmaf(h.y * rr.y, t.y, acc);
            acc = fmaf(h.z * rr.z, t.z, acc);
            acc = fmaf(h.w * rr.w, t.w, acc);
        }
#pragma unroll
        for (int off = 32; off; off >>= 1) acc += __shfl_down(acc, off, 64);
        if (lane == 0) out[e] = fminf(fmaxf(acc, 0.f), 1.f);
    }
}

extern "C" void kernel_launch(void* const* d_in, const int* in_sizes, int n_in,
                              void* d_out, int out_size, void* d_ws, size_t ws_size,
                              hipStream_t stream) {
    const float* x_drug    = (const float*)d_in[0];
    const float* x_protein = (const float*)d_in[1];
    const float* rel_ddi   = (const float*)d_in[2];
    const float* rel_dpi   = (const float*)d_in[3];
    const int* ddi_src = (const int*)d_in[4];
    const int* ddi_dst = (const int*)d_in[5];
    const int* dpi_src = (const int*)d_in[6];
    const int* dpi_dst = (const int*)d_in[7];
    const int* ppi_src = (const int*)d_in[8];
    const int* ppi_dst = (const int*)d_in[9];

    const int D  = in_sizes[2];              // 2048
    const int nd = in_sizes[0] / D;          // N_DRUG
    const int np = in_sizes[1] / D;          // N_PROT
    const int E  = in_sizes[4];              // edges per relation
    float* out = (float*)d_out;

    const int ndp = ((nd + 63) / 64) * 64;   // 64-aligned
    const int npp = ((np + 63) / 64) * 64;
    const int CB  = 2 * ndp + npp;           // buckets: (rel, src)

    const size_t b_d16 = (size_t)nd * D * 2; // fp16 mirror sizes (16B-aligned)
    const size_t b_p16 = (size_t)np * D * 2;
    const size_t ints_sort = (size_t)(2 * CB + 16 + 6 * E) * sizeof(int);
    const size_t need_sort = ints_sort;
    const size_t need_full = b_d16 + b_p16 + ints_sort;

    if (ws_size < need_sort) {               // last resort: direct kernel
        edge_score_all<<<2048, 256, 0, stream>>>(
            (const float4*)x_drug, (const float4*)x_protein,
            (const float4*)rel_ddi, (const float4*)rel_dpi,
            ddi_src, ddi_dst, dpi_src, dpi_dst, ppi_src, ppi_dst, out, E);
        return;
    }

    const bool full = (ws_size >= need_full);
    char* wp = (char*)d_ws;
    __half* drug16 = nullptr; __half* prot16 = nullptr;
    if (full) {
        drug16 = (__half*)wp;  wp += b_d16;  // 16B-aligned (D*2 = 4096B rows)
        prot16 = (__half*)wp;  wp += b_p16;
    }
    int* cnt    = (int*)wp;                  // CB
    int* aux    = cnt + CB;                  // 16: cursors[0..2], queue at [8]
    int* base   = aux + 16;                  // CB
    int* sorted = base + CB;                 // 3E (edge ids, src-grouped)
    int* sd     = sorted + 3 * E;            // 3E ((src<<16)|dst)

    if (full) {
        cvt_zero<<<2048, 256, 0, stream>>>(
            (const float4*)x_drug, (const float4*)x_protein,
            drug16, prot16, nd * (D / 4), np * (D / 4), cnt, CB + 16);
    } else {
        zero_ints<<<(CB + 16 + 255) / 256, 256, 0, stream>>>(cnt, CB + 16);
    }
    hist3<<<1024, 256, 0, stream>>>(ddi_src, dpi_src, ppi_src, E, cnt, ndp);
    alloc3<<<(CB + 255) / 256, 256, 0, stream>>>(cnt, base, aux, ndp, CB);
    scatter3<<<1024, 256, 0, stream>>>(ddi_src, ddi_dst, dpi_src, dpi_dst,
                                       ppi_src, ppi_dst, E, base, ndp, sorted, sd);

    if (full) {
        score16<<<2048, 256, 0, stream>>>(
            (const float4*)drug16, (const float4*)prot16,
            (const float4*)x_drug, (const float4*)x_protein,
            (const float4*)rel_ddi, (const float4*)rel_dpi,
            sorted, sd, aux + 8, out, E);
    } else {
        score_f32<<<2048, 256, 0, stream>>>(
            (const float4*)x_drug, (const float4*)x_protein,
            (const float4*)rel_ddi, (const float4*)rel_dpi,
            sorted, sd, out, E);
    }
}